// Round 6
// baseline (636.231 us; speedup 1.0000x reference)
//
#include <hip/hip_runtime.h>
#include <hip/hip_bf16.h>

typedef __attribute__((ext_vector_type(8))) short short8_t;
typedef __attribute__((ext_vector_type(8))) unsigned short ushort8_t;
typedef __attribute__((ext_vector_type(4))) float f32x4;

#define SCALE 0.125f   // 64^-0.5

__device__ __forceinline__ unsigned short f32_to_bf16_rne(float f) {
  unsigned int u = __float_as_uint(f);
  unsigned int r = 0x7FFFu + ((u >> 16) & 1u);
  return (unsigned short)((u + r) >> 16);
}

// bank-spread swizzle for 64B rows (32 j * bf16): slot' = slot ^ swz(row)
__device__ __forceinline__ int swz(int i) { return (i + (i >> 2)) & 3; }

// ---------------- cast x (fp32 -> bf16) ----------------
__global__ __launch_bounds__(256) void cast_x_kernel(const float4* __restrict__ in,
                                                     ushort4* __restrict__ out, int n4) {
  int i = blockIdx.x * 256 + threadIdx.x;
  if (i < n4) {
    float4 v = in[i];
    ushort4 o;
    o.x = f32_to_bf16_rne(v.x); o.y = f32_to_bf16_rne(v.y);
    o.z = f32_to_bf16_rne(v.z); o.w = f32_to_bf16_rne(v.w);
    out[i] = o;
  }
}

// ---------------- transpose + cast weights: in R x C fp32 -> out C x R bf16 ----------------
__global__ __launch_bounds__(256) void transpose_cast_kernel(const float* __restrict__ in,
                                                             unsigned short* __restrict__ out,
                                                             int R, int C) {
  __shared__ float tile[32][33];
  int c0 = blockIdx.x * 32, r0 = blockIdx.y * 32;
  int tx = threadIdx.x & 31, ty = threadIdx.x >> 5;  // 32 x 8
  #pragma unroll
  for (int i = ty; i < 32; i += 8)
    tile[i][tx] = in[(long)(r0 + i) * C + c0 + tx];
  __syncthreads();
  #pragma unroll
  for (int i = ty; i < 32; i += 8)
    out[(long)(c0 + i) * R + r0 + tx] = f32_to_bf16_rne(tile[tx][i]);
}

// ---------------- transpose V: Vt[b][h][d][j] = KV[b*1024+j][768+h*64+d] ----------------
// j-slots (16B) within each 32-j tile are XOR-swizzled by d so pv2 can stage
// linearly and still read bank-conflict-free (pre-swizzled-source pattern).
__global__ __launch_bounds__(256) void transpose_v_kernel(const unsigned short* __restrict__ KV,
                                                          unsigned short* __restrict__ Vt) {
  __shared__ unsigned short tile[64][72];
  const int j0 = blockIdx.x * 64, h = blockIdx.y, b = blockIdx.z;
  const int tid = threadIdx.x;
  for (int c = tid; c < 512; c += 256) {
    int j = c >> 3, dp = (c & 7) * 8;
    *(ushort8_t*)&tile[j][dp] =
        *(const ushort8_t*)&KV[(long)(b * 1024 + j0 + j) * 1536 + 768 + h * 64 + dp];
  }
  __syncthreads();
  for (int c = tid; c < 512; c += 256) {
    int d = c >> 3, jp = (c & 7) * 8;
    ushort8_t v;
    #pragma unroll
    for (int t = 0; t < 8; t++) v[t] = tile[jp + t][d];
    int jg = j0 + jp;
    int jt_ = jg >> 5;            // 32-j tile
    int u = (jg >> 3) & 3;        // 16B slot within tile
    *(ushort8_t*)&Vt[((long)(b * 12 + h) * 64 + d) * 1024 + (jt_ << 5) + ((u ^ swz(d)) << 3)] = v;
  }
}

// ---------------- NT GEMM (projections / out-proj). SUM2: A := A + A2 (bf16) ----------------
template <int BM, int BN, bool OUT_F32, bool BIAS, bool SUM2>
__global__ __launch_bounds__(256) void gemm_nt(const unsigned short* __restrict__ A,
                                               const unsigned short* __restrict__ A2, int lda,
                                               const unsigned short* __restrict__ B, int ldb,
                                               void* __restrict__ Cv, int ldc,
                                               const float* __restrict__ bias,
                                               int M, int N, int K) {
  constexpr int BK = 32;
  constexpr int LDT = BK + 8;
  __shared__ unsigned short As[BM][LDT];
  __shared__ unsigned short Bs[BN][LDT];
  const int m0 = blockIdx.y * BM;
  const int n0 = blockIdx.x * BN;
  const int tid = threadIdx.x;
  const int lane = tid & 63;
  const int w = tid >> 6;
  constexpr int WM = BM / 2, WN = BN / 2;
  constexpr int FM = WM / 16, FN = WN / 16;
  const int wr = w >> 1, wc = w & 1;

  f32x4 acc[FM][FN];
  #pragma unroll
  for (int a = 0; a < FM; a++)
    #pragma unroll
    for (int b2 = 0; b2 < FN; b2++) acc[a][b2] = (f32x4){0.f, 0.f, 0.f, 0.f};

  const int rl = lane & 15;
  const int kq = (lane >> 4) * 8;

  for (int k0 = 0; k0 < K; k0 += BK) {
    __syncthreads();
    for (int c = tid; c < BM * (BK / 8); c += 256) {
      int row = c >> 2, kp = (c & 3) * 8;
      ushort8_t v = *(const ushort8_t*)&A[(long)(m0 + row) * lda + k0 + kp];
      if (SUM2) {
        ushort8_t v2 = *(const ushort8_t*)&A2[(long)(m0 + row) * lda + k0 + kp];
        #pragma unroll
        for (int x = 0; x < 8; ++x)
          v[x] = f32_to_bf16_rne(__uint_as_float((unsigned)v[x] << 16) +
                                 __uint_as_float((unsigned)v2[x] << 16));
      }
      *(ushort8_t*)&As[row][kp] = v;
    }
    for (int c = tid; c < BN * (BK / 8); c += 256) {
      int row = c >> 2, kp = (c & 3) * 8;
      *(ushort8_t*)&Bs[row][kp] = *(const ushort8_t*)&B[(long)(n0 + row) * ldb + k0 + kp];
    }
    __syncthreads();
    short8_t af[FM], bfr[FN];
    #pragma unroll
    for (int fm = 0; fm < FM; fm++) af[fm] = *(const short8_t*)&As[wr * WM + fm * 16 + rl][kq];
    #pragma unroll
    for (int fn = 0; fn < FN; fn++) bfr[fn] = *(const short8_t*)&Bs[wc * WN + fn * 16 + rl][kq];
    #pragma unroll
    for (int fm = 0; fm < FM; fm++)
      #pragma unroll
      for (int fn = 0; fn < FN; fn++)
        acc[fm][fn] = __builtin_amdgcn_mfma_f32_16x16x32_bf16(af[fm], bfr[fn], acc[fm][fn], 0, 0, 0);
  }

  const int rq4 = (lane >> 4) * 4;
  #pragma unroll
  for (int fm = 0; fm < FM; fm++)
    #pragma unroll
    for (int fn = 0; fn < FN; fn++)
      #pragma unroll
      for (int j = 0; j < 4; j++) {
        int row = m0 + wr * WM + fm * 16 + rq4 + j;
        int col = n0 + wc * WN + fn * 16 + rl;
        float v = acc[fm][fn][j];
        if (BIAS) v += bias[col];
        if (OUT_F32)
          ((float*)Cv)[(long)row * ldc + col] = v;
        else
          ((unsigned short*)Cv)[(long)row * ldc + col] = f32_to_bf16_rne(v);
      }
}

// ---------------- X: QK^T (all heads) + mix_pre + exp -> E tiles + partial row sums ----------------
// Block = (jt, it, zc): 64 i x 32 j. A/B MFMA fragments loaded DIRECTLY from
// global (16B/lane contiguous, L1/L2-hot) -- no staging LDS, no in-loop
// barriers. LDS = 48KB end-of-kernel E repack only -> 3 blocks/CU.
// E chunk = 48KB per (zc,jt,it): 4 sub-chunks [g(12)][16 i][32 j] (12KB each,
// slot16' = jslot ^ swz(i&15)). Stores contiguous per instruction (no 192B
// stride -> no partial-sector write amplification).
__global__ __launch_bounds__(256, 3) void qk_mix_exp_kernel(
    const unsigned short* __restrict__ Qb, const unsigned short* __restrict__ KVb,
    const float* __restrict__ mix_pre,
    unsigned short* __restrict__ Eo, float* __restrict__ Lpart, int b_base) {
  __shared__ unsigned short Ebuf[24576];  // 48KB repack
  __shared__ float mpre_s[144];
  const int jt = blockIdx.x, it = blockIdx.y, z = blockIdx.z;
  const int b = b_base + z;
  const int tid = threadIdx.x, lane = tid & 63, w = tid >> 6;
  const int r15 = lane & 15, q = lane >> 4;
  if (tid < 144) mpre_s[tid] = mix_pre[tid] * SCALE;
  __syncthreads();
  const int i0 = it * 64, j0 = jt * 32;

  // per-lane global row bases (16B frag loads)
  const long qrow  = (long)(b * 1024 + i0 + w * 16 + r15) * 768 + q * 8;
  const long krow0 = (long)(b * 1024 + j0 + r15) * 1536 + q * 8;
  const long krow1 = (long)(b * 1024 + j0 + 16 + r15) * 1536 + q * 8;

  float macc[12][2][4];  // [g][j-frag][e]
  #pragma unroll
  for (int g = 0; g < 12; ++g)
    #pragma unroll
    for (int nf = 0; nf < 2; ++nf)
      #pragma unroll
      for (int e = 0; e < 4; ++e) macc[g][nf][e] = 0.f;

  #pragma unroll 2
  for (int h = 0; h < 12; ++h) {
    const int kb = h * 64;
    short8_t a0  = *(const short8_t*)&Qb[qrow + kb];
    short8_t a1  = *(const short8_t*)&Qb[qrow + kb + 32];
    short8_t b00 = *(const short8_t*)&KVb[krow0 + kb];
    short8_t b01 = *(const short8_t*)&KVb[krow0 + kb + 32];
    short8_t b10 = *(const short8_t*)&KVb[krow1 + kb];
    short8_t b11 = *(const short8_t*)&KVb[krow1 + kb + 32];
    f32x4 h0 = {0.f, 0.f, 0.f, 0.f}, h1 = {0.f, 0.f, 0.f, 0.f};
    h0 = __builtin_amdgcn_mfma_f32_16x16x32_bf16(a0, b00, h0, 0, 0, 0);
    h0 = __builtin_amdgcn_mfma_f32_16x16x32_bf16(a1, b01, h0, 0, 0, 0);
    h1 = __builtin_amdgcn_mfma_f32_16x16x32_bf16(a0, b10, h1, 0, 0, 0);
    h1 = __builtin_amdgcn_mfma_f32_16x16x32_bf16(a1, b11, h1, 0, 0, 0);
    #pragma unroll
    for (int g = 0; g < 12; ++g) {
      const float wgt = mpre_s[h * 12 + g];
      #pragma unroll
      for (int e = 0; e < 4; ++e) {
        macc[g][0][e] += wgt * h0[e];
        macc[g][1][e] += wgt * h1[e];
      }
    }
  }

  // exp (no max needed: mixed-logit |max| small, fp32 headroom ample)
  #pragma unroll
  for (int g = 0; g < 12; ++g)
    #pragma unroll
    for (int nf = 0; nf < 2; ++nf)
      #pragma unroll
      for (int e = 0; e < 4; ++e) macc[g][nf][e] = __expf(macc[g][nf][e]);

  // partial row sums over this block's 32 j
  float ls[12][4];
  #pragma unroll
  for (int g = 0; g < 12; ++g)
    #pragma unroll
    for (int e = 0; e < 4; ++e) ls[g][e] = macc[g][0][e] + macc[g][1][e];
  #pragma unroll
  for (int off = 1; off < 16; off <<= 1)
    #pragma unroll
    for (int g = 0; g < 12; ++g)
      #pragma unroll
      for (int e = 0; e < 4; ++e) ls[g][e] += __shfl_xor(ls[g][e], off);
  #pragma unroll
  for (int g = 0; g < 12; ++g)
    if (r15 == g) {
      #pragma unroll
      for (int e = 0; e < 4; ++e)
        Lpart[((long)(z * 32 + jt) * 12 + g) * 1024 + i0 + w * 16 + q * 4 + e] = ls[g][e];
    }

  // repack E: [sub=w][g][r=i&15][32 j], slot' = jslot ^ swz(r)
  #pragma unroll
  for (int g = 0; g < 12; ++g)
    #pragma unroll
    for (int nf = 0; nf < 2; ++nf)
      #pragma unroll
      for (int e = 0; e < 4; ++e) {
        const int r = q * 4 + e;
        const int jsl = nf * 2 + (r15 >> 3);
        Ebuf[(w * 12 + g) * 512 + r * 32 + ((jsl ^ swz(r)) << 3) + (r15 & 7)] =
            f32_to_bf16_rne(macc[g][nf][e]);
      }
  __syncthreads();
  const long cb = ((long)((z * 32 + jt) * 16 + it)) * 24576;
  #pragma unroll
  for (int u = 0; u < 12; ++u)
    *(ushort8_t*)&Eo[cb + (u * 256 + tid) * 8] = *(const ushort8_t*)&Ebuf[(u * 256 + tid) * 8];
}

// ---------------- Y: invl[zc][g][i] = 1 / sum_jt Lpart ----------------
__global__ __launch_bounds__(256) void lsum_kernel(const float* __restrict__ Lpart,
                                                   float* __restrict__ invl, int nb) {
  int id = blockIdx.x * 256 + threadIdx.x;
  if (id >= nb * 12288) return;
  int z = id / 12288, r = id - z * 12288;
  float s = 0.f;
  #pragma unroll 4
  for (int jt = 0; jt < 32; ++jt) s += Lpart[((long)(z * 32 + jt)) * 12288 + r];
  invl[id] = 1.f / s;
}

// ---------------- Z: P'' build + PV, E read exactly once ----------------
// Block = (it16, jh, zc): 16 i-rows, ALL 12 g2, j in [jh*512, jh*512+512).
// Per jt: stage E sub-chunk (12KB) + V slice (48KB) linearly (reg prefetch,
// swizzle pre-baked); transform -> P''[12][16][32] bf16; 12 MFMA/wave.
__global__ __launch_bounds__(256, 2) void pv2_kernel(
    const unsigned short* __restrict__ E, const unsigned short* __restrict__ Vt,
    const float* __restrict__ invl, const float* __restrict__ mix_post,
    unsigned short* __restrict__ AOp0, unsigned short* __restrict__ AOp1, int b_base) {
  __shared__ unsigned short Ebuf[6144];   // [g][16 i][32 j] swizzled
  __shared__ unsigned short Vbuf[24576];  // [g2*64+d][32 j] swizzled
  __shared__ unsigned short Pbuf[6144];   // [g2][16 i][32 j] swizzled
  const int it = blockIdx.x, jh = blockIdx.y, zc = blockIdx.z;
  const int b = b_base + zc;
  const int tid = threadIdx.x, lane = tid & 63, w = tid >> 6;
  const int r15 = lane & 15, q = lane >> 4;
  const int i_loc = tid & 15, jslot = (tid >> 4) & 3;  // transform mapping; g2-group = w

  // combined weights W2[r][g] = mpost[g, w*3+r] * invl[g, i]
  float W2[3][12];
  #pragma unroll
  for (int g = 0; g < 12; ++g) {
    float il = invl[(zc * 12 + g) * 1024 + it * 16 + i_loc];
    #pragma unroll
    for (int r = 0; r < 3; ++r) W2[r][g] = mix_post[g * 12 + w * 3 + r] * il;
  }

  f32x4 acc[3][4];
  #pragma unroll
  for (int gl = 0; gl < 3; ++gl)
    #pragma unroll
    for (int df = 0; df < 4; ++df) acc[gl][df] = (f32x4){0.f, 0.f, 0.f, 0.f};

  const long vbase = (long)(b * 12) * 64 * 1024;
  ushort8_t ereg[3], vreg[12];
  auto loadE = [&](int jt) {
    const long cbs = ((long)((zc * 32 + jt) * 16 + (it >> 2))) * 24576 + (it & 3) * 6144;
    #pragma unroll
    for (int u = 0; u < 3; ++u)
      ereg[u] = *(const ushort8_t*)&E[cbs + (u * 256 + tid) * 8];
  };
  auto loadV = [&](int jt) {
    #pragma unroll
    for (int u = 0; u < 12; ++u) {
      int unit = u * 256 + tid;  // gd = unit>>2, slot = unit&3
      vreg[u] = *(const ushort8_t*)&Vt[vbase + (long)(unit >> 2) * 1024 + jt * 32 +
                                       ((unit & 3) << 3)];
    }
  };
  const int jt0 = jh * 16;
  loadE(jt0);
  loadV(jt0);

  for (int t = 0; t < 16; ++t) {
    __syncthreads();  // buffers free (prev PV done)
    #pragma unroll
    for (int u = 0; u < 3; ++u) *(ushort8_t*)&Ebuf[(u * 256 + tid) * 8] = ereg[u];
    #pragma unroll
    for (int u = 0; u < 12; ++u) *(ushort8_t*)&Vbuf[(u * 256 + tid) * 8] = vreg[u];
    __syncthreads();  // staged
    if (t < 15) { loadE(jt0 + t + 1); loadV(jt0 + t + 1); }  // prefetch overlaps compute

    // transform: P''[g2][i][j] = sum_g W2[g2][g] * E[g][i][j]
    float p[3][8];
    #pragma unroll
    for (int r = 0; r < 3; ++r)
      #pragma unroll
      for (int jj = 0; jj < 8; ++jj) p[r][jj] = 0.f;
    const int esl = (jslot ^ swz(i_loc)) << 3;
    #pragma unroll
    for (int g = 0; g < 12; ++g) {
      ushort8_t ev = *(const ushort8_t*)&Ebuf[g * 512 + i_loc * 32 + esl];
      #pragma unroll
      for (int jj = 0; jj < 8; ++jj) {
        float ef = __uint_as_float((unsigned)ev[jj] << 16);
        #pragma unroll
        for (int r = 0; r < 3; ++r) p[r][jj] += W2[r][g] * ef;
      }
    }
    #pragma unroll
    for (int r = 0; r < 3; ++r) {
      ushort8_t pv;
      #pragma unroll
      for (int jj = 0; jj < 8; ++jj) pv[jj] = f32_to_bf16_rne(p[r][jj]);
      *(ushort8_t*)&Pbuf[(w * 3 + r) * 512 + i_loc * 32 + esl] = pv;
    }
    __syncthreads();  // P ready

    // PV: wave w owns g2 = w*3 .. w*3+2; k = 32 j per MFMA
    #pragma unroll
    for (int gl = 0; gl < 3; ++gl) {
      const int g2 = w * 3 + gl;
      short8_t af = *(const short8_t*)&Pbuf[g2 * 512 + r15 * 32 + ((q ^ swz(r15)) << 3)];
      #pragma unroll
      for (int df = 0; df < 4; ++df) {
        short8_t bf = *(const short8_t*)&Vbuf[(g2 * 64 + df * 16 + r15) * 32 +
                                              ((q ^ swz(r15)) << 3)];
        acc[gl][df] = __builtin_amdgcn_mfma_f32_16x16x32_bf16(af, bf, acc[gl][df], 0, 0, 0);
      }
    }
  }

  unsigned short* AOp = jh ? AOp1 : AOp0;
  #pragma unroll
  for (int gl = 0; gl < 3; ++gl) {
    const int g2 = w * 3 + gl;
    #pragma unroll
    for (int df = 0; df < 4; ++df)
      #pragma unroll
      for (int e = 0; e < 4; ++e) {
        int row = it * 16 + q * 4 + e;
        int col = g2 * 64 + df * 16 + r15;
        AOp[(long)(b * 1024 + row) * 768 + col] = f32_to_bf16_rne(acc[gl][df][e]);
      }
  }
}

// ---------------- host launch ----------------
extern "C" void kernel_launch(void* const* d_in, const int* in_sizes, int n_in,
                              void* d_out, int out_size, void* d_ws, size_t ws_size,
                              hipStream_t stream) {
  const float* x        = (const float*)d_in[0];
  const float* W_q      = (const float*)d_in[1];
  const float* W_kv     = (const float*)d_in[2];
  const float* mix_pre  = (const float*)d_in[3];
  const float* mix_post = (const float*)d_in[4];
  const float* W_out    = (const float*)d_in[5];
  const float* b_out    = (const float*)d_in[6];
  float* out = (float*)d_out;

  char* p = (char*)d_ws;
  auto alloc = [&](size_t bytes) { char* r = p; p += (bytes + 255) & ~(size_t)255; return r; };
  unsigned short* xb    = (unsigned short*)alloc(8192ull * 768 * 2);
  unsigned short* WqT   = (unsigned short*)alloc(768ull * 768 * 2);
  unsigned short* WkvT  = (unsigned short*)alloc(1536ull * 768 * 2);
  unsigned short* WoutT = (unsigned short*)alloc(768ull * 768 * 2);
  unsigned short* Qb    = (unsigned short*)alloc(8192ull * 768 * 2);
  unsigned short* KVb   = (unsigned short*)alloc(8192ull * 1536 * 2);
  unsigned short* Vt    = (unsigned short*)alloc(8ull * 12 * 64 * 1024 * 2);
  unsigned short* AOp0  = (unsigned short*)alloc(8192ull * 768 * 2);
  unsigned short* AOp1  = (unsigned short*)alloc(8192ull * 768 * 2);

  // chunking: nz batches of E/Lpart in flight per round (ws-gated; nz=2 needs
  // ~146 MB which is proven available).
  const int nz = (ws_size >= 322000000ull) ? 8 : (ws_size >= 211000000ull) ? 4 : 2;
  unsigned short* E     = (unsigned short*)alloc((size_t)nz * 32 * 16 * 24576 * 2);
  float*          Lpart = (float*)alloc((size_t)nz * 32 * 12 * 1024 * 4);
  float*          invl  = (float*)alloc((size_t)nz * 12 * 1024 * 4);

  // 1) casts / transposes
  cast_x_kernel<<<6144, 256, 0, stream>>>((const float4*)x, (ushort4*)xb, 8192 * 768 / 4);
  transpose_cast_kernel<<<dim3(24, 24), 256, 0, stream>>>(W_q, WqT, 768, 768);
  transpose_cast_kernel<<<dim3(48, 24), 256, 0, stream>>>(W_kv, WkvT, 768, 1536);
  transpose_cast_kernel<<<dim3(24, 24), 256, 0, stream>>>(W_out, WoutT, 768, 768);

  // 2) projections
  gemm_nt<128, 128, false, false, false><<<dim3(6, 64), 256, 0, stream>>>(
      xb, nullptr, 768, WqT, 768, Qb, 768, nullptr, 8192, 768, 768);
  gemm_nt<128, 128, false, false, false><<<dim3(12, 64), 256, 0, stream>>>(
      xb, nullptr, 768, WkvT, 768, KVb, 1536, nullptr, 8192, 1536, 768);

  // 3) V transpose (pre-swizzled j-slots)
  transpose_v_kernel<<<dim3(16, 12, 8), 256, 0, stream>>>(KVb, Vt);

  // 4) attention middle, nz batches per round
  for (int b0 = 0; b0 < 8; b0 += nz) {
    qk_mix_exp_kernel<<<dim3(32, 16, nz), 256, 0, stream>>>(Qb, KVb, mix_pre, E, Lpart, b0);
    lsum_kernel<<<nz * 48, 256, 0, stream>>>(Lpart, invl, nz);
    pv2_kernel<<<dim3(64, 2, nz), 256, 0, stream>>>(E, Vt, invl, mix_post, AOp0, AOp1, b0);
  }

  // 5) out = (AOp0 + AOp1) @ WoutT^T + b_out (fp32 out)
  gemm_nt<128, 128, true, true, true><<<dim3(6, 64), 256, 0, stream>>>(
      AOp0, AOp1, 768, WoutT, 768, out, 768, b_out, 8192, 768, 768);
}

// Round 7
// 501.375 us; speedup vs baseline: 1.2690x; 1.2690x over previous
//
#include <hip/hip_runtime.h>
#include <hip/hip_bf16.h>

typedef __attribute__((ext_vector_type(8))) short short8_t;
typedef __attribute__((ext_vector_type(8))) unsigned short ushort8_t;
typedef __attribute__((ext_vector_type(4))) float f32x4;

#define SCALE 0.125f   // 64^-0.5

__device__ __forceinline__ unsigned short f32_to_bf16_rne(float f) {
  unsigned int u = __float_as_uint(f);
  unsigned int r = 0x7FFFu + ((u >> 16) & 1u);
  return (unsigned short)((u + r) >> 16);
}

// bank-spread swizzle for 64B rows (32 j * bf16): slot' = slot ^ swz(row)
__device__ __forceinline__ int swz(int i) { return (i + (i >> 2)) & 3; }

// ---------------- cast x (fp32 -> bf16) ----------------
__global__ __launch_bounds__(256) void cast_x_kernel(const float4* __restrict__ in,
                                                     ushort4* __restrict__ out, int n4) {
  int i = blockIdx.x * 256 + threadIdx.x;
  if (i < n4) {
    float4 v = in[i];
    ushort4 o;
    o.x = f32_to_bf16_rne(v.x); o.y = f32_to_bf16_rne(v.y);
    o.z = f32_to_bf16_rne(v.z); o.w = f32_to_bf16_rne(v.w);
    out[i] = o;
  }
}

// ---------------- transpose + cast weights: in R x C fp32 -> out C x R bf16 ----------------
__global__ __launch_bounds__(256) void transpose_cast_kernel(const float* __restrict__ in,
                                                             unsigned short* __restrict__ out,
                                                             int R, int C) {
  __shared__ float tile[32][33];
  int c0 = blockIdx.x * 32, r0 = blockIdx.y * 32;
  int tx = threadIdx.x & 31, ty = threadIdx.x >> 5;  // 32 x 8
  #pragma unroll
  for (int i = ty; i < 32; i += 8)
    tile[i][tx] = in[(long)(r0 + i) * C + c0 + tx];
  __syncthreads();
  #pragma unroll
  for (int i = ty; i < 32; i += 8)
    out[(long)(c0 + i) * R + r0 + tx] = f32_to_bf16_rne(tile[tx][i]);
}

// ---------------- transpose V: Vt[b][h][d][j] = KV[b*1024+j][768+h*64+d] ----------------
// j-slots (16B) within each 32-j tile are XOR-swizzled by d so pv2 can stage
// linearly and still read bank-conflict-free (pre-swizzled-source pattern).
__global__ __launch_bounds__(256) void transpose_v_kernel(const unsigned short* __restrict__ KV,
                                                          unsigned short* __restrict__ Vt) {
  __shared__ unsigned short tile[64][72];
  const int j0 = blockIdx.x * 64, h = blockIdx.y, b = blockIdx.z;
  const int tid = threadIdx.x;
  for (int c = tid; c < 512; c += 256) {
    int j = c >> 3, dp = (c & 7) * 8;
    *(ushort8_t*)&tile[j][dp] =
        *(const ushort8_t*)&KV[(long)(b * 1024 + j0 + j) * 1536 + 768 + h * 64 + dp];
  }
  __syncthreads();
  for (int c = tid; c < 512; c += 256) {
    int d = c >> 3, jp = (c & 7) * 8;
    ushort8_t v;
    #pragma unroll
    for (int t = 0; t < 8; t++) v[t] = tile[jp + t][d];
    int jg = j0 + jp;
    int jt_ = jg >> 5;            // 32-j tile
    int u = (jg >> 3) & 3;        // 16B slot within tile
    *(ushort8_t*)&Vt[((long)(b * 12 + h) * 64 + d) * 1024 + (jt_ << 5) + ((u ^ swz(d)) << 3)] = v;
  }
}

// ---------------- NT GEMM (projections / out-proj). SUM2: A := A + A2 (bf16) ----------------
template <int BM, int BN, bool OUT_F32, bool BIAS, bool SUM2>
__global__ __launch_bounds__(256) void gemm_nt(const unsigned short* __restrict__ A,
                                               const unsigned short* __restrict__ A2, int lda,
                                               const unsigned short* __restrict__ B, int ldb,
                                               void* __restrict__ Cv, int ldc,
                                               const float* __restrict__ bias,
                                               int M, int N, int K) {
  constexpr int BK = 32;
  constexpr int LDT = BK + 8;
  __shared__ unsigned short As[BM][LDT];
  __shared__ unsigned short Bs[BN][LDT];
  const int m0 = blockIdx.y * BM;
  const int n0 = blockIdx.x * BN;
  const int tid = threadIdx.x;
  const int lane = tid & 63;
  const int w = tid >> 6;
  constexpr int WM = BM / 2, WN = BN / 2;
  constexpr int FM = WM / 16, FN = WN / 16;
  const int wr = w >> 1, wc = w & 1;

  f32x4 acc[FM][FN];
  #pragma unroll
  for (int a = 0; a < FM; a++)
    #pragma unroll
    for (int b2 = 0; b2 < FN; b2++) acc[a][b2] = (f32x4){0.f, 0.f, 0.f, 0.f};

  const int rl = lane & 15;
  const int kq = (lane >> 4) * 8;

  for (int k0 = 0; k0 < K; k0 += BK) {
    __syncthreads();
    for (int c = tid; c < BM * (BK / 8); c += 256) {
      int row = c >> 2, kp = (c & 3) * 8;
      ushort8_t v = *(const ushort8_t*)&A[(long)(m0 + row) * lda + k0 + kp];
      if (SUM2) {
        ushort8_t v2 = *(const ushort8_t*)&A2[(long)(m0 + row) * lda + k0 + kp];
        #pragma unroll
        for (int x = 0; x < 8; ++x)
          v[x] = f32_to_bf16_rne(__uint_as_float((unsigned)v[x] << 16) +
                                 __uint_as_float((unsigned)v2[x] << 16));
      }
      *(ushort8_t*)&As[row][kp] = v;
    }
    for (int c = tid; c < BN * (BK / 8); c += 256) {
      int row = c >> 2, kp = (c & 3) * 8;
      *(ushort8_t*)&Bs[row][kp] = *(const ushort8_t*)&B[(long)(n0 + row) * ldb + k0 + kp];
    }
    __syncthreads();
    short8_t af[FM], bfr[FN];
    #pragma unroll
    for (int fm = 0; fm < FM; fm++) af[fm] = *(const short8_t*)&As[wr * WM + fm * 16 + rl][kq];
    #pragma unroll
    for (int fn = 0; fn < FN; fn++) bfr[fn] = *(const short8_t*)&Bs[wc * WN + fn * 16 + rl][kq];
    #pragma unroll
    for (int fm = 0; fm < FM; fm++)
      #pragma unroll
      for (int fn = 0; fn < FN; fn++)
        acc[fm][fn] = __builtin_amdgcn_mfma_f32_16x16x32_bf16(af[fm], bfr[fn], acc[fm][fn], 0, 0, 0);
  }

  const int rq4 = (lane >> 4) * 4;
  #pragma unroll
  for (int fm = 0; fm < FM; fm++)
    #pragma unroll
    for (int fn = 0; fn < FN; fn++)
      #pragma unroll
      for (int j = 0; j < 4; j++) {
        int row = m0 + wr * WM + fm * 16 + rq4 + j;
        int col = n0 + wc * WN + fn * 16 + rl;
        float v = acc[fm][fn][j];
        if (BIAS) v += bias[col];
        if (OUT_F32)
          ((float*)Cv)[(long)row * ldc + col] = v;
        else
          ((unsigned short*)Cv)[(long)row * ldc + col] = f32_to_bf16_rne(v);
      }
}

// ---------------- X: QK^T (all heads) + mix_pre + exp -> E tiles + partial row sums ----------------
// Block = (jt, it, zc): 64 i x 32 j. A/B MFMA fragments loaded DIRECTLY from
// global (16B/lane contiguous, L1/L2-hot) -- no staging LDS, no in-loop
// barriers. LDS = 48KB end-of-kernel E repack only -> 3 blocks/CU.
__global__ __launch_bounds__(256, 3) void qk_mix_exp_kernel(
    const unsigned short* __restrict__ Qb, const unsigned short* __restrict__ KVb,
    const float* __restrict__ mix_pre,
    unsigned short* __restrict__ Eo, float* __restrict__ Lpart, int b_base) {
  __shared__ unsigned short Ebuf[24576];  // 48KB repack
  __shared__ float mpre_s[144];
  const int jt = blockIdx.x, it = blockIdx.y, z = blockIdx.z;
  const int b = b_base + z;
  const int tid = threadIdx.x, lane = tid & 63, w = tid >> 6;
  const int r15 = lane & 15, q = lane >> 4;
  if (tid < 144) mpre_s[tid] = mix_pre[tid] * SCALE;
  __syncthreads();
  const int i0 = it * 64, j0 = jt * 32;

  // per-lane global row bases (16B frag loads)
  const long qrow  = (long)(b * 1024 + i0 + w * 16 + r15) * 768 + q * 8;
  const long krow0 = (long)(b * 1024 + j0 + r15) * 1536 + q * 8;
  const long krow1 = (long)(b * 1024 + j0 + 16 + r15) * 1536 + q * 8;

  float macc[12][2][4];  // [g][j-frag][e]
  #pragma unroll
  for (int g = 0; g < 12; ++g)
    #pragma unroll
    for (int nf = 0; nf < 2; ++nf)
      #pragma unroll
      for (int e = 0; e < 4; ++e) macc[g][nf][e] = 0.f;

  #pragma unroll 2
  for (int h = 0; h < 12; ++h) {
    const int kb = h * 64;
    short8_t a0  = *(const short8_t*)&Qb[qrow + kb];
    short8_t a1  = *(const short8_t*)&Qb[qrow + kb + 32];
    short8_t b00 = *(const short8_t*)&KVb[krow0 + kb];
    short8_t b01 = *(const short8_t*)&KVb[krow0 + kb + 32];
    short8_t b10 = *(const short8_t*)&KVb[krow1 + kb];
    short8_t b11 = *(const short8_t*)&KVb[krow1 + kb + 32];
    f32x4 h0 = {0.f, 0.f, 0.f, 0.f}, h1 = {0.f, 0.f, 0.f, 0.f};
    h0 = __builtin_amdgcn_mfma_f32_16x16x32_bf16(a0, b00, h0, 0, 0, 0);
    h0 = __builtin_amdgcn_mfma_f32_16x16x32_bf16(a1, b01, h0, 0, 0, 0);
    h1 = __builtin_amdgcn_mfma_f32_16x16x32_bf16(a0, b10, h1, 0, 0, 0);
    h1 = __builtin_amdgcn_mfma_f32_16x16x32_bf16(a1, b11, h1, 0, 0, 0);
    #pragma unroll
    for (int g = 0; g < 12; ++g) {
      const float wgt = mpre_s[h * 12 + g];
      #pragma unroll
      for (int e = 0; e < 4; ++e) {
        macc[g][0][e] += wgt * h0[e];
        macc[g][1][e] += wgt * h1[e];
      }
    }
  }

  // exp (no max needed: mixed-logit |max| small, fp32 headroom ample)
  #pragma unroll
  for (int g = 0; g < 12; ++g)
    #pragma unroll
    for (int nf = 0; nf < 2; ++nf)
      #pragma unroll
      for (int e = 0; e < 4; ++e) macc[g][nf][e] = __expf(macc[g][nf][e]);

  // partial row sums over this block's 32 j
  float ls[12][4];
  #pragma unroll
  for (int g = 0; g < 12; ++g)
    #pragma unroll
    for (int e = 0; e < 4; ++e) ls[g][e] = macc[g][0][e] + macc[g][1][e];
  #pragma unroll
  for (int off = 1; off < 16; off <<= 1)
    #pragma unroll
    for (int g = 0; g < 12; ++g)
      #pragma unroll
      for (int e = 0; e < 4; ++e) ls[g][e] += __shfl_xor(ls[g][e], off);
  #pragma unroll
  for (int g = 0; g < 12; ++g)
    if (r15 == g) {
      #pragma unroll
      for (int e = 0; e < 4; ++e)
        Lpart[((long)(z * 32 + jt) * 12 + g) * 1024 + i0 + w * 16 + q * 4 + e] = ls[g][e];
    }

  // repack E: [sub=w][g][r=i&15][32 j], slot' = jslot ^ swz(r)
  #pragma unroll
  for (int g = 0; g < 12; ++g)
    #pragma unroll
    for (int nf = 0; nf < 2; ++nf)
      #pragma unroll
      for (int e = 0; e < 4; ++e) {
        const int r = q * 4 + e;
        const int jsl = nf * 2 + (r15 >> 3);
        Ebuf[(w * 12 + g) * 512 + r * 32 + ((jsl ^ swz(r)) << 3) + (r15 & 7)] =
            f32_to_bf16_rne(macc[g][nf][e]);
      }
  __syncthreads();
  const long cb = ((long)((z * 32 + jt) * 16 + it)) * 24576;
  #pragma unroll
  for (int u = 0; u < 12; ++u)
    *(ushort8_t*)&Eo[cb + (u * 256 + tid) * 8] = *(const ushort8_t*)&Ebuf[(u * 256 + tid) * 8];
}

// ---------------- Y: invl[zc][g][i] = 1 / sum_jt Lpart ----------------
__global__ __launch_bounds__(256) void lsum_kernel(const float* __restrict__ Lpart,
                                                   float* __restrict__ invl, int nb) {
  int id = blockIdx.x * 256 + threadIdx.x;
  if (id >= nb * 12288) return;
  int z = id / 12288, r = id - z * 12288;
  float s = 0.f;
  #pragma unroll 4
  for (int jt = 0; jt < 32; ++jt) s += Lpart[((long)(z * 32 + jt)) * 12288 + r];
  invl[id] = 1.f / s;
}

// ---------------- Z: P'' build + PV, E read exactly once ----------------
// Block = (it16, jh, zc): 16 i-rows, ALL 12 g2, j in [jh*512, jh*512+512).
// __launch_bounds__(256, 1): DO NOT raise the min-waves hint -- (256,2) caps
// the allocator at 128 VGPRs and the ereg/vreg prefetch (+acc+W2, ~190 VGPRs)
// spills to scratch (round-6 regression: 157MB WRITE_SIZE of spill traffic).
// Occupancy is LDS-capped at 2 blocks/CU regardless (72KB).
__global__ __launch_bounds__(256, 1) void pv2_kernel(
    const unsigned short* __restrict__ E, const unsigned short* __restrict__ Vt,
    const float* __restrict__ invl, const float* __restrict__ mix_post,
    unsigned short* __restrict__ AOp0, unsigned short* __restrict__ AOp1, int b_base) {
  __shared__ unsigned short Ebuf[6144];   // [g][16 i][32 j] swizzled
  __shared__ unsigned short Vbuf[24576];  // [g2*64+d][32 j] swizzled
  __shared__ unsigned short Pbuf[6144];   // [g2][16 i][32 j] swizzled
  const int it = blockIdx.x, jh = blockIdx.y, zc = blockIdx.z;
  const int b = b_base + zc;
  const int tid = threadIdx.x, lane = tid & 63, w = tid >> 6;
  const int r15 = lane & 15, q = lane >> 4;
  const int i_loc = tid & 15, jslot = (tid >> 4) & 3;  // transform mapping; g2-group = w

  // combined weights W2[r][g] = mpost[g, w*3+r] * invl[g, i]
  float W2[3][12];
  #pragma unroll
  for (int g = 0; g < 12; ++g) {
    float il = invl[(zc * 12 + g) * 1024 + it * 16 + i_loc];
    #pragma unroll
    for (int r = 0; r < 3; ++r) W2[r][g] = mix_post[g * 12 + w * 3 + r] * il;
  }

  f32x4 acc[3][4];
  #pragma unroll
  for (int gl = 0; gl < 3; ++gl)
    #pragma unroll
    for (int df = 0; df < 4; ++df) acc[gl][df] = (f32x4){0.f, 0.f, 0.f, 0.f};

  const long vbase = (long)(b * 12) * 64 * 1024;
  ushort8_t ereg[3], vreg[12];
  auto loadE = [&](int jt) {
    const long cbs = ((long)((zc * 32 + jt) * 16 + (it >> 2))) * 24576 + (it & 3) * 6144;
    #pragma unroll
    for (int u = 0; u < 3; ++u)
      ereg[u] = *(const ushort8_t*)&E[cbs + (u * 256 + tid) * 8];
  };
  auto loadV = [&](int jt) {
    #pragma unroll
    for (int u = 0; u < 12; ++u) {
      int unit = u * 256 + tid;  // gd = unit>>2, slot = unit&3
      vreg[u] = *(const ushort8_t*)&Vt[vbase + (long)(unit >> 2) * 1024 + jt * 32 +
                                       ((unit & 3) << 3)];
    }
  };
  const int jt0 = jh * 16;
  loadE(jt0);
  loadV(jt0);

  for (int t = 0; t < 16; ++t) {
    __syncthreads();  // buffers free (prev PV done)
    #pragma unroll
    for (int u = 0; u < 3; ++u) *(ushort8_t*)&Ebuf[(u * 256 + tid) * 8] = ereg[u];
    #pragma unroll
    for (int u = 0; u < 12; ++u) *(ushort8_t*)&Vbuf[(u * 256 + tid) * 8] = vreg[u];
    __syncthreads();  // staged
    if (t < 15) { loadE(jt0 + t + 1); loadV(jt0 + t + 1); }  // prefetch overlaps compute

    // transform: P''[g2][i][j] = sum_g W2[g2][g] * E[g][i][j]
    float p[3][8];
    #pragma unroll
    for (int r = 0; r < 3; ++r)
      #pragma unroll
      for (int jj = 0; jj < 8; ++jj) p[r][jj] = 0.f;
    const int esl = (jslot ^ swz(i_loc)) << 3;
    #pragma unroll
    for (int g = 0; g < 12; ++g) {
      ushort8_t ev = *(const ushort8_t*)&Ebuf[g * 512 + i_loc * 32 + esl];
      #pragma unroll
      for (int jj = 0; jj < 8; ++jj) {
        float ef = __uint_as_float((unsigned)ev[jj] << 16);
        #pragma unroll
        for (int r = 0; r < 3; ++r) p[r][jj] += W2[r][g] * ef;
      }
    }
    #pragma unroll
    for (int r = 0; r < 3; ++r) {
      ushort8_t pv;
      #pragma unroll
      for (int jj = 0; jj < 8; ++jj) pv[jj] = f32_to_bf16_rne(p[r][jj]);
      *(ushort8_t*)&Pbuf[(w * 3 + r) * 512 + i_loc * 32 + esl] = pv;
    }
    __syncthreads();  // P ready

    // PV: wave w owns g2 = w*3 .. w*3+2; k = 32 j per MFMA
    #pragma unroll
    for (int gl = 0; gl < 3; ++gl) {
      const int g2 = w * 3 + gl;
      short8_t af = *(const short8_t*)&Pbuf[g2 * 512 + r15 * 32 + ((q ^ swz(r15)) << 3)];
      #pragma unroll
      for (int df = 0; df < 4; ++df) {
        short8_t bf = *(const short8_t*)&Vbuf[(g2 * 64 + df * 16 + r15) * 32 +
                                              ((q ^ swz(r15)) << 3)];
        acc[gl][df] = __builtin_amdgcn_mfma_f32_16x16x32_bf16(af, bf, acc[gl][df], 0, 0, 0);
      }
    }
  }

  unsigned short* AOp = jh ? AOp1 : AOp0;
  #pragma unroll
  for (int gl = 0; gl < 3; ++gl) {
    const int g2 = w * 3 + gl;
    #pragma unroll
    for (int df = 0; df < 4; ++df)
      #pragma unroll
      for (int e = 0; e < 4; ++e) {
        int row = it * 16 + q * 4 + e;
        int col = g2 * 64 + df * 16 + r15;
        AOp[(long)(b * 1024 + row) * 768 + col] = f32_to_bf16_rne(acc[gl][df][e]);
      }
  }
}

// ---------------- host launch ----------------
extern "C" void kernel_launch(void* const* d_in, const int* in_sizes, int n_in,
                              void* d_out, int out_size, void* d_ws, size_t ws_size,
                              hipStream_t stream) {
  const float* x        = (const float*)d_in[0];
  const float* W_q      = (const float*)d_in[1];
  const float* W_kv     = (const float*)d_in[2];
  const float* mix_pre  = (const float*)d_in[3];
  const float* mix_post = (const float*)d_in[4];
  const float* W_out    = (const float*)d_in[5];
  const float* b_out    = (const float*)d_in[6];
  float* out = (float*)d_out;

  char* p = (char*)d_ws;
  auto alloc = [&](size_t bytes) { char* r = p; p += (bytes + 255) & ~(size_t)255; return r; };
  unsigned short* xb    = (unsigned short*)alloc(8192ull * 768 * 2);
  unsigned short* WqT   = (unsigned short*)alloc(768ull * 768 * 2);
  unsigned short* WkvT  = (unsigned short*)alloc(1536ull * 768 * 2);
  unsigned short* WoutT = (unsigned short*)alloc(768ull * 768 * 2);
  unsigned short* Qb    = (unsigned short*)alloc(8192ull * 768 * 2);
  unsigned short* KVb   = (unsigned short*)alloc(8192ull * 1536 * 2);
  unsigned short* Vt    = (unsigned short*)alloc(8ull * 12 * 64 * 1024 * 2);
  unsigned short* AOp0  = (unsigned short*)alloc(8192ull * 768 * 2);
  unsigned short* AOp1  = (unsigned short*)alloc(8192ull * 768 * 2);

  // chunking: nz batches of E/Lpart in flight per round (ws-gated; nz=2 needs
  // ~146 MB which is proven available).
  const int nz = (ws_size >= 322000000ull) ? 8 : (ws_size >= 211000000ull) ? 4 : 2;
  unsigned short* E     = (unsigned short*)alloc((size_t)nz * 32 * 16 * 24576 * 2);
  float*          Lpart = (float*)alloc((size_t)nz * 32 * 12 * 1024 * 4);
  float*          invl  = (float*)alloc((size_t)nz * 12 * 1024 * 4);

  // 1) casts / transposes
  cast_x_kernel<<<6144, 256, 0, stream>>>((const float4*)x, (ushort4*)xb, 8192 * 768 / 4);
  transpose_cast_kernel<<<dim3(24, 24), 256, 0, stream>>>(W_q, WqT, 768, 768);
  transpose_cast_kernel<<<dim3(48, 24), 256, 0, stream>>>(W_kv, WkvT, 768, 1536);
  transpose_cast_kernel<<<dim3(24, 24), 256, 0, stream>>>(W_out, WoutT, 768, 768);

  // 2) projections
  gemm_nt<128, 128, false, false, false><<<dim3(6, 64), 256, 0, stream>>>(
      xb, nullptr, 768, WqT, 768, Qb, 768, nullptr, 8192, 768, 768);
  gemm_nt<128, 128, false, false, false><<<dim3(12, 64), 256, 0, stream>>>(
      xb, nullptr, 768, WkvT, 768, KVb, 1536, nullptr, 8192, 1536, 768);

  // 3) V transpose (pre-swizzled j-slots)
  transpose_v_kernel<<<dim3(16, 12, 8), 256, 0, stream>>>(KVb, Vt);

  // 4) attention middle, nz batches per round
  for (int b0 = 0; b0 < 8; b0 += nz) {
    qk_mix_exp_kernel<<<dim3(32, 16, nz), 256, 0, stream>>>(Qb, KVb, mix_pre, E, Lpart, b0);
    lsum_kernel<<<nz * 48, 256, 0, stream>>>(Lpart, invl, nz);
    pv2_kernel<<<dim3(64, 2, nz), 256, 0, stream>>>(E, Vt, invl, mix_post, AOp0, AOp1, b0);
  }

  // 5) out = (AOp0 + AOp1) @ WoutT^T + b_out (fp32 out)
  gemm_nt<128, 128, true, true, true><<<dim3(6, 64), 256, 0, stream>>>(
      AOp0, AOp1, 768, WoutT, 768, out, 768, b_out, 8192, 768, 768);
}

// Round 8
// 457.299 us; speedup vs baseline: 1.3913x; 1.0964x over previous
//
#include <hip/hip_runtime.h>
#include <hip/hip_bf16.h>

typedef __attribute__((ext_vector_type(8))) short short8_t;
typedef __attribute__((ext_vector_type(8))) unsigned short ushort8_t;
typedef __attribute__((ext_vector_type(4))) float f32x4;

#define SCALE 0.125f   // 64^-0.5

__device__ __forceinline__ unsigned short f32_to_bf16_rne(float f) {
  unsigned int u = __float_as_uint(f);
  unsigned int r = 0x7FFFu + ((u >> 16) & 1u);
  return (unsigned short)((u + r) >> 16);
}

// bank-spread swizzle for 64B rows (32 j * bf16): slot' = slot ^ swz(row)
__device__ __forceinline__ int swz(int i) { return (i + (i >> 2)) & 3; }

// ---------------- cast x (fp32 -> bf16) ----------------
__global__ __launch_bounds__(256) void cast_x_kernel(const float4* __restrict__ in,
                                                     ushort4* __restrict__ out, int n4) {
  int i = blockIdx.x * 256 + threadIdx.x;
  if (i < n4) {
    float4 v = in[i];
    ushort4 o;
    o.x = f32_to_bf16_rne(v.x); o.y = f32_to_bf16_rne(v.y);
    o.z = f32_to_bf16_rne(v.z); o.w = f32_to_bf16_rne(v.w);
    out[i] = o;
  }
}

// ---------------- transpose + cast weights: in R x C fp32 -> out C x R bf16 ----------------
__global__ __launch_bounds__(256) void transpose_cast_kernel(const float* __restrict__ in,
                                                             unsigned short* __restrict__ out,
                                                             int R, int C) {
  __shared__ float tile[32][33];
  int c0 = blockIdx.x * 32, r0 = blockIdx.y * 32;
  int tx = threadIdx.x & 31, ty = threadIdx.x >> 5;  // 32 x 8
  #pragma unroll
  for (int i = ty; i < 32; i += 8)
    tile[i][tx] = in[(long)(r0 + i) * C + c0 + tx];
  __syncthreads();
  #pragma unroll
  for (int i = ty; i < 32; i += 8)
    out[(long)(c0 + i) * R + r0 + tx] = f32_to_bf16_rne(tile[tx][i]);
}

// ---------------- transpose V: Vt[b][h][d][j] = KV[b*1024+j][768+h*64+d] ----------------
// j-slots (16B) within each 32-j tile are XOR-swizzled by d so pv2 can stage
// linearly and still read bank-conflict-free (pre-swizzled-source pattern).
__global__ __launch_bounds__(256) void transpose_v_kernel(const unsigned short* __restrict__ KV,
                                                          unsigned short* __restrict__ Vt) {
  __shared__ unsigned short tile[64][72];
  const int j0 = blockIdx.x * 64, h = blockIdx.y, b = blockIdx.z;
  const int tid = threadIdx.x;
  for (int c = tid; c < 512; c += 256) {
    int j = c >> 3, dp = (c & 7) * 8;
    *(ushort8_t*)&tile[j][dp] =
        *(const ushort8_t*)&KV[(long)(b * 1024 + j0 + j) * 1536 + 768 + h * 64 + dp];
  }
  __syncthreads();
  for (int c = tid; c < 512; c += 256) {
    int d = c >> 3, jp = (c & 7) * 8;
    ushort8_t v;
    #pragma unroll
    for (int t = 0; t < 8; t++) v[t] = tile[jp + t][d];
    int jg = j0 + jp;
    int jt_ = jg >> 5;            // 32-j tile
    int u = (jg >> 3) & 3;        // 16B slot within tile
    *(ushort8_t*)&Vt[((long)(b * 12 + h) * 64 + d) * 1024 + (jt_ << 5) + ((u ^ swz(d)) << 3)] = v;
  }
}

// ---------------- NT GEMM (projections / out-proj). SUM2: A := A + A2 (bf16) ----------------
template <int BM, int BN, bool OUT_F32, bool BIAS, bool SUM2>
__global__ __launch_bounds__(256) void gemm_nt(const unsigned short* __restrict__ A,
                                               const unsigned short* __restrict__ A2, int lda,
                                               const unsigned short* __restrict__ B, int ldb,
                                               void* __restrict__ Cv, int ldc,
                                               const float* __restrict__ bias,
                                               int M, int N, int K) {
  constexpr int BK = 32;
  constexpr int LDT = BK + 8;
  __shared__ unsigned short As[BM][LDT];
  __shared__ unsigned short Bs[BN][LDT];
  const int m0 = blockIdx.y * BM;
  const int n0 = blockIdx.x * BN;
  const int tid = threadIdx.x;
  const int lane = tid & 63;
  const int w = tid >> 6;
  constexpr int WM = BM / 2, WN = BN / 2;
  constexpr int FM = WM / 16, FN = WN / 16;
  const int wr = w >> 1, wc = w & 1;

  f32x4 acc[FM][FN];
  #pragma unroll
  for (int a = 0; a < FM; a++)
    #pragma unroll
    for (int b2 = 0; b2 < FN; b2++) acc[a][b2] = (f32x4){0.f, 0.f, 0.f, 0.f};

  const int rl = lane & 15;
  const int kq = (lane >> 4) * 8;

  for (int k0 = 0; k0 < K; k0 += BK) {
    __syncthreads();
    for (int c = tid; c < BM * (BK / 8); c += 256) {
      int row = c >> 2, kp = (c & 3) * 8;
      ushort8_t v = *(const ushort8_t*)&A[(long)(m0 + row) * lda + k0 + kp];
      if (SUM2) {
        ushort8_t v2 = *(const ushort8_t*)&A2[(long)(m0 + row) * lda + k0 + kp];
        #pragma unroll
        for (int x = 0; x < 8; ++x)
          v[x] = f32_to_bf16_rne(__uint_as_float((unsigned)v[x] << 16) +
                                 __uint_as_float((unsigned)v2[x] << 16));
      }
      *(ushort8_t*)&As[row][kp] = v;
    }
    for (int c = tid; c < BN * (BK / 8); c += 256) {
      int row = c >> 2, kp = (c & 3) * 8;
      *(ushort8_t*)&Bs[row][kp] = *(const ushort8_t*)&B[(long)(n0 + row) * ldb + k0 + kp];
    }
    __syncthreads();
    short8_t af[FM], bfr[FN];
    #pragma unroll
    for (int fm = 0; fm < FM; fm++) af[fm] = *(const short8_t*)&As[wr * WM + fm * 16 + rl][kq];
    #pragma unroll
    for (int fn = 0; fn < FN; fn++) bfr[fn] = *(const short8_t*)&Bs[wc * WN + fn * 16 + rl][kq];
    #pragma unroll
    for (int fm = 0; fm < FM; fm++)
      #pragma unroll
      for (int fn = 0; fn < FN; fn++)
        acc[fm][fn] = __builtin_amdgcn_mfma_f32_16x16x32_bf16(af[fm], bfr[fn], acc[fm][fn], 0, 0, 0);
  }

  const int rq4 = (lane >> 4) * 4;
  #pragma unroll
  for (int fm = 0; fm < FM; fm++)
    #pragma unroll
    for (int fn = 0; fn < FN; fn++)
      #pragma unroll
      for (int j = 0; j < 4; j++) {
        int row = m0 + wr * WM + fm * 16 + rq4 + j;
        int col = n0 + wc * WN + fn * 16 + rl;
        float v = acc[fm][fn][j];
        if (BIAS) v += bias[col];
        if (OUT_F32)
          ((float*)Cv)[(long)row * ldc + col] = v;
        else
          ((unsigned short*)Cv)[(long)row * ldc + col] = f32_to_bf16_rne(v);
      }
}

// ---------------- X: QK^T (all heads) + mix_pre + exp -> E tiles + partial row sums ----------------
// Block = (jt, it, zc): 64 i x 32 j. A/B MFMA fragments loaded DIRECTLY from
// global (16B/lane contiguous, L1/L2-hot) -- no staging LDS, no in-loop
// barriers. LDS = 48KB end-of-kernel E repack only -> 3 blocks/CU (LDS-capped).
// __launch_bounds__(256, 1): macc[12][2][4] = 96 f32 live + 6 frag regs needs
// ~150 VGPRs. A min-waves hint of 3 capped the allocator at 84 VGPRs -> scratch
// spill (round 7: 176MB WRITE_SIZE, 133us). Same lesson as pv2 round 6.
__global__ __launch_bounds__(256, 1) void qk_mix_exp_kernel(
    const unsigned short* __restrict__ Qb, const unsigned short* __restrict__ KVb,
    const float* __restrict__ mix_pre,
    unsigned short* __restrict__ Eo, float* __restrict__ Lpart, int b_base) {
  __shared__ unsigned short Ebuf[24576];  // 48KB repack
  __shared__ float mpre_s[144];
  const int jt = blockIdx.x, it = blockIdx.y, z = blockIdx.z;
  const int b = b_base + z;
  const int tid = threadIdx.x, lane = tid & 63, w = tid >> 6;
  const int r15 = lane & 15, q = lane >> 4;
  if (tid < 144) mpre_s[tid] = mix_pre[tid] * SCALE;
  __syncthreads();
  const int i0 = it * 64, j0 = jt * 32;

  // per-lane global row bases (16B frag loads)
  const long qrow  = (long)(b * 1024 + i0 + w * 16 + r15) * 768 + q * 8;
  const long krow0 = (long)(b * 1024 + j0 + r15) * 1536 + q * 8;
  const long krow1 = (long)(b * 1024 + j0 + 16 + r15) * 1536 + q * 8;

  float macc[12][2][4];  // [g][j-frag][e]
  #pragma unroll
  for (int g = 0; g < 12; ++g)
    #pragma unroll
    for (int nf = 0; nf < 2; ++nf)
      #pragma unroll
      for (int e = 0; e < 4; ++e) macc[g][nf][e] = 0.f;

  for (int h = 0; h < 12; ++h) {
    const int kb = h * 64;
    short8_t a0  = *(const short8_t*)&Qb[qrow + kb];
    short8_t a1  = *(const short8_t*)&Qb[qrow + kb + 32];
    short8_t b00 = *(const short8_t*)&KVb[krow0 + kb];
    short8_t b01 = *(const short8_t*)&KVb[krow0 + kb + 32];
    short8_t b10 = *(const short8_t*)&KVb[krow1 + kb];
    short8_t b11 = *(const short8_t*)&KVb[krow1 + kb + 32];
    f32x4 h0 = {0.f, 0.f, 0.f, 0.f}, h1 = {0.f, 0.f, 0.f, 0.f};
    h0 = __builtin_amdgcn_mfma_f32_16x16x32_bf16(a0, b00, h0, 0, 0, 0);
    h0 = __builtin_amdgcn_mfma_f32_16x16x32_bf16(a1, b01, h0, 0, 0, 0);
    h1 = __builtin_amdgcn_mfma_f32_16x16x32_bf16(a0, b10, h1, 0, 0, 0);
    h1 = __builtin_amdgcn_mfma_f32_16x16x32_bf16(a1, b11, h1, 0, 0, 0);
    #pragma unroll
    for (int g = 0; g < 12; ++g) {
      const float wgt = mpre_s[h * 12 + g];
      #pragma unroll
      for (int e = 0; e < 4; ++e) {
        macc[g][0][e] += wgt * h0[e];
        macc[g][1][e] += wgt * h1[e];
      }
    }
  }

  // exp (no max needed: mixed-logit |max| small, fp32 headroom ample)
  #pragma unroll
  for (int g = 0; g < 12; ++g)
    #pragma unroll
    for (int nf = 0; nf < 2; ++nf)
      #pragma unroll
      for (int e = 0; e < 4; ++e) macc[g][nf][e] = __expf(macc[g][nf][e]);

  // partial row sums over this block's 32 j
  float ls[12][4];
  #pragma unroll
  for (int g = 0; g < 12; ++g)
    #pragma unroll
    for (int e = 0; e < 4; ++e) ls[g][e] = macc[g][0][e] + macc[g][1][e];
  #pragma unroll
  for (int off = 1; off < 16; off <<= 1)
    #pragma unroll
    for (int g = 0; g < 12; ++g)
      #pragma unroll
      for (int e = 0; e < 4; ++e) ls[g][e] += __shfl_xor(ls[g][e], off);
  #pragma unroll
  for (int g = 0; g < 12; ++g)
    if (r15 == g) {
      #pragma unroll
      for (int e = 0; e < 4; ++e)
        Lpart[((long)(z * 32 + jt) * 12 + g) * 1024 + i0 + w * 16 + q * 4 + e] = ls[g][e];
    }

  // repack E: [sub=w][g][r=i&15][32 j], slot' = jslot ^ swz(r)
  #pragma unroll
  for (int g = 0; g < 12; ++g)
    #pragma unroll
    for (int nf = 0; nf < 2; ++nf)
      #pragma unroll
      for (int e = 0; e < 4; ++e) {
        const int r = q * 4 + e;
        const int jsl = nf * 2 + (r15 >> 3);
        Ebuf[(w * 12 + g) * 512 + r * 32 + ((jsl ^ swz(r)) << 3) + (r15 & 7)] =
            f32_to_bf16_rne(macc[g][nf][e]);
      }
  __syncthreads();
  const long cb = ((long)((z * 32 + jt) * 16 + it)) * 24576;
  #pragma unroll
  for (int u = 0; u < 12; ++u)
    *(ushort8_t*)&Eo[cb + (u * 256 + tid) * 8] = *(const ushort8_t*)&Ebuf[(u * 256 + tid) * 8];
}

// ---------------- Y: invl[zc][g][i] = 1 / sum_jt Lpart ----------------
__global__ __launch_bounds__(256) void lsum_kernel(const float* __restrict__ Lpart,
                                                   float* __restrict__ invl, int nb) {
  int id = blockIdx.x * 256 + threadIdx.x;
  if (id >= nb * 12288) return;
  int z = id / 12288, r = id - z * 12288;
  float s = 0.f;
  #pragma unroll 4
  for (int jt = 0; jt < 32; ++jt) s += Lpart[((long)(z * 32 + jt)) * 12288 + r];
  invl[id] = 1.f / s;
}

// ---------------- Z: P'' build + PV, E read exactly once ----------------
// Block = (it16, jh, zc): 16 i-rows, ALL 12 g2, j in [jh*512, jh*512+512).
// __launch_bounds__(256, 1): DO NOT raise the min-waves hint -- (256,2) caps
// the allocator at 128 VGPRs and the ereg/vreg prefetch (+acc+W2, ~190 VGPRs)
// spills to scratch (round-6 regression: 157MB WRITE_SIZE of spill traffic).
// Occupancy is LDS-capped at 2 blocks/CU regardless (72KB).
__global__ __launch_bounds__(256, 1) void pv2_kernel(
    const unsigned short* __restrict__ E, const unsigned short* __restrict__ Vt,
    const float* __restrict__ invl, const float* __restrict__ mix_post,
    unsigned short* __restrict__ AOp0, unsigned short* __restrict__ AOp1, int b_base) {
  __shared__ unsigned short Ebuf[6144];   // [g][16 i][32 j] swizzled
  __shared__ unsigned short Vbuf[24576];  // [g2*64+d][32 j] swizzled
  __shared__ unsigned short Pbuf[6144];   // [g2][16 i][32 j] swizzled
  const int it = blockIdx.x, jh = blockIdx.y, zc = blockIdx.z;
  const int b = b_base + zc;
  const int tid = threadIdx.x, lane = tid & 63, w = tid >> 6;
  const int r15 = lane & 15, q = lane >> 4;
  const int i_loc = tid & 15, jslot = (tid >> 4) & 3;  // transform mapping; g2-group = w

  // combined weights W2[r][g] = mpost[g, w*3+r] * invl[g, i]
  float W2[3][12];
  #pragma unroll
  for (int g = 0; g < 12; ++g) {
    float il = invl[(zc * 12 + g) * 1024 + it * 16 + i_loc];
    #pragma unroll
    for (int r = 0; r < 3; ++r) W2[r][g] = mix_post[g * 12 + w * 3 + r] * il;
  }

  f32x4 acc[3][4];
  #pragma unroll
  for (int gl = 0; gl < 3; ++gl)
    #pragma unroll
    for (int df = 0; df < 4; ++df) acc[gl][df] = (f32x4){0.f, 0.f, 0.f, 0.f};

  const long vbase = (long)(b * 12) * 64 * 1024;
  ushort8_t ereg[3], vreg[12];
  auto loadE = [&](int jt) {
    const long cbs = ((long)((zc * 32 + jt) * 16 + (it >> 2))) * 24576 + (it & 3) * 6144;
    #pragma unroll
    for (int u = 0; u < 3; ++u)
      ereg[u] = *(const ushort8_t*)&E[cbs + (u * 256 + tid) * 8];
  };
  auto loadV = [&](int jt) {
    #pragma unroll
    for (int u = 0; u < 12; ++u) {
      int unit = u * 256 + tid;  // gd = unit>>2, slot = unit&3
      vreg[u] = *(const ushort8_t*)&Vt[vbase + (long)(unit >> 2) * 1024 + jt * 32 +
                                       ((unit & 3) << 3)];
    }
  };
  const int jt0 = jh * 16;
  loadE(jt0);
  loadV(jt0);

  for (int t = 0; t < 16; ++t) {
    __syncthreads();  // buffers free (prev PV done)
    #pragma unroll
    for (int u = 0; u < 3; ++u) *(ushort8_t*)&Ebuf[(u * 256 + tid) * 8] = ereg[u];
    #pragma unroll
    for (int u = 0; u < 12; ++u) *(ushort8_t*)&Vbuf[(u * 256 + tid) * 8] = vreg[u];
    __syncthreads();  // staged
    if (t < 15) { loadE(jt0 + t + 1); loadV(jt0 + t + 1); }  // prefetch overlaps compute

    // transform: P''[g2][i][j] = sum_g W2[g2][g] * E[g][i][j]
    float p[3][8];
    #pragma unroll
    for (int r = 0; r < 3; ++r)
      #pragma unroll
      for (int jj = 0; jj < 8; ++jj) p[r][jj] = 0.f;
    const int esl = (jslot ^ swz(i_loc)) << 3;
    #pragma unroll
    for (int g = 0; g < 12; ++g) {
      ushort8_t ev = *(const ushort8_t*)&Ebuf[g * 512 + i_loc * 32 + esl];
      #pragma unroll
      for (int jj = 0; jj < 8; ++jj) {
        float ef = __uint_as_float((unsigned)ev[jj] << 16);
        #pragma unroll
        for (int r = 0; r < 3; ++r) p[r][jj] += W2[r][g] * ef;
      }
    }
    #pragma unroll
    for (int r = 0; r < 3; ++r) {
      ushort8_t pv;
      #pragma unroll
      for (int jj = 0; jj < 8; ++jj) pv[jj] = f32_to_bf16_rne(p[r][jj]);
      *(ushort8_t*)&Pbuf[(w * 3 + r) * 512 + i_loc * 32 + esl] = pv;
    }
    __syncthreads();  // P ready

    // PV: wave w owns g2 = w*3 .. w*3+2; k = 32 j per MFMA
    #pragma unroll
    for (int gl = 0; gl < 3; ++gl) {
      const int g2 = w * 3 + gl;
      short8_t af = *(const short8_t*)&Pbuf[g2 * 512 + r15 * 32 + ((q ^ swz(r15)) << 3)];
      #pragma unroll
      for (int df = 0; df < 4; ++df) {
        short8_t bf = *(const short8_t*)&Vbuf[(g2 * 64 + df * 16 + r15) * 32 +
                                              ((q ^ swz(r15)) << 3)];
        acc[gl][df] = __builtin_amdgcn_mfma_f32_16x16x32_bf16(af, bf, acc[gl][df], 0, 0, 0);
      }
    }
  }

  unsigned short* AOp = jh ? AOp1 : AOp0;
  #pragma unroll
  for (int gl = 0; gl < 3; ++gl) {
    const int g2 = w * 3 + gl;
    #pragma unroll
    for (int df = 0; df < 4; ++df)
      #pragma unroll
      for (int e = 0; e < 4; ++e) {
        int row = it * 16 + q * 4 + e;
        int col = g2 * 64 + df * 16 + r15;
        AOp[(long)(b * 1024 + row) * 768 + col] = f32_to_bf16_rne(acc[gl][df][e]);
      }
  }
}

// ---------------- host launch ----------------
extern "C" void kernel_launch(void* const* d_in, const int* in_sizes, int n_in,
                              void* d_out, int out_size, void* d_ws, size_t ws_size,
                              hipStream_t stream) {
  const float* x        = (const float*)d_in[0];
  const float* W_q      = (const float*)d_in[1];
  const float* W_kv     = (const float*)d_in[2];
  const float* mix_pre  = (const float*)d_in[3];
  const float* mix_post = (const float*)d_in[4];
  const float* W_out    = (const float*)d_in[5];
  const float* b_out    = (const float*)d_in[6];
  float* out = (float*)d_out;

  char* p = (char*)d_ws;
  auto alloc = [&](size_t bytes) { char* r = p; p += (bytes + 255) & ~(size_t)255; return r; };
  unsigned short* xb    = (unsigned short*)alloc(8192ull * 768 * 2);
  unsigned short* WqT   = (unsigned short*)alloc(768ull * 768 * 2);
  unsigned short* WkvT  = (unsigned short*)alloc(1536ull * 768 * 2);
  unsigned short* WoutT = (unsigned short*)alloc(768ull * 768 * 2);
  unsigned short* Qb    = (unsigned short*)alloc(8192ull * 768 * 2);
  unsigned short* KVb   = (unsigned short*)alloc(8192ull * 1536 * 2);
  unsigned short* Vt    = (unsigned short*)alloc(8ull * 12 * 64 * 1024 * 2);
  unsigned short* AOp0  = (unsigned short*)alloc(8192ull * 768 * 2);
  unsigned short* AOp1  = (unsigned short*)alloc(8192ull * 768 * 2);

  // chunking: nz batches of E/Lpart in flight per round (ws-gated; nz=2 needs
  // ~146 MB which is proven available).
  const int nz = (ws_size >= 322000000ull) ? 8 : (ws_size >= 211000000ull) ? 4 : 2;
  unsigned short* E     = (unsigned short*)alloc((size_t)nz * 32 * 16 * 24576 * 2);
  float*          Lpart = (float*)alloc((size_t)nz * 32 * 12 * 1024 * 4);
  float*          invl  = (float*)alloc((size_t)nz * 12 * 1024 * 4);

  // 1) casts / transposes
  cast_x_kernel<<<6144, 256, 0, stream>>>((const float4*)x, (ushort4*)xb, 8192 * 768 / 4);
  transpose_cast_kernel<<<dim3(24, 24), 256, 0, stream>>>(W_q, WqT, 768, 768);
  transpose_cast_kernel<<<dim3(48, 24), 256, 0, stream>>>(W_kv, WkvT, 768, 1536);
  transpose_cast_kernel<<<dim3(24, 24), 256, 0, stream>>>(W_out, WoutT, 768, 768);

  // 2) projections
  gemm_nt<128, 128, false, false, false><<<dim3(6, 64), 256, 0, stream>>>(
      xb, nullptr, 768, WqT, 768, Qb, 768, nullptr, 8192, 768, 768);
  gemm_nt<128, 128, false, false, false><<<dim3(12, 64), 256, 0, stream>>>(
      xb, nullptr, 768, WkvT, 768, KVb, 1536, nullptr, 8192, 1536, 768);

  // 3) V transpose (pre-swizzled j-slots)
  transpose_v_kernel<<<dim3(16, 12, 8), 256, 0, stream>>>(KVb, Vt);

  // 4) attention middle, nz batches per round
  for (int b0 = 0; b0 < 8; b0 += nz) {
    qk_mix_exp_kernel<<<dim3(32, 16, nz), 256, 0, stream>>>(Qb, KVb, mix_pre, E, Lpart, b0);
    lsum_kernel<<<nz * 48, 256, 0, stream>>>(Lpart, invl, nz);
    pv2_kernel<<<dim3(64, 2, nz), 256, 0, stream>>>(E, Vt, invl, mix_post, AOp0, AOp1, b0);
  }

  // 5) out = (AOp0 + AOp1) @ WoutT^T + b_out (fp32 out)
  gemm_nt<128, 128, true, true, true><<<dim3(6, 64), 256, 0, stream>>>(
      AOp0, AOp1, 768, WoutT, 768, out, 768, b_out, 8192, 768, 768);
}